// Round 12
// baseline (274.280 us; speedup 1.0000x reference)
//
#include <hip/hip_runtime.h>
#include <math.h>

// SelfAttention fused pipeline, MI355X gfx950.
// B=4 S=2048 D=1024 H=8 DK=128.
// R3: flash v2 — S^T orientation, 32x32x16 MFMA, exp-only softmax (bounded
// scores), mask folded into V-zeroing + l via mask-MFMA, in-register P
// transpose, split K/V LDS buffers, DMA prefetch in the compute shadow.
// R4: T5 s_setprio(1) around flash2 MFMA clusters (small/free, kept).
// R7/R9/R10 FAILED: reg caps spill; novel LDS layouts bank-conflict.
// LESSONS: flash2 reg-bound 2 blocks/CU; NO novel LDS layouts.
// R12: gemm dbuf +1.3us. R13: flash2 XCD-affinity swizzle — FETCH
// 139->24.7MB, dur 91->88.8; flash2 at structure ceiling (staging latency
// not critical path). R14: gemm mega-step BK=64 (dup'd verified BK=32
// slices, dbuf, 16 barriers) — total 275.8->266.0 (-9.8us): gemm WAS
// drain-bound. BK=128 rejected (128KB LDS -> 1 block/CU, m132).
// R15: gemm grid-axis swap. Old x=M fast: 64 consecutive blocks share one
// 256KB B-panel but stream ALL 16MB of A per N-stripe, 24x = 384MB A
// demand -> FETCH 136MB (6x over compulsory ~22MB). New x=N fast:
// consecutive blocks share a 256KB A-panel (L2-resident, 24x reuse) and
// stream B — B is only 6MB (proj 2MB), fits aggregate L2/L3, absorbed
// on-die. Two-line index change + launch dims.

typedef __bf16 bf16;
typedef __bf16 bf16x2 __attribute__((ext_vector_type(2)));
typedef __bf16 bf16x4 __attribute__((ext_vector_type(4)));
typedef __bf16 bf16x8 __attribute__((ext_vector_type(8)));
typedef float  f32x4  __attribute__((ext_vector_type(4)));
typedef float  f32x16 __attribute__((ext_vector_type(16)));
typedef int    i32x4  __attribute__((ext_vector_type(4)));

constexpr float QK_SCALE = 0.08838834764831845f;  // 1/sqrt(128)

__device__ __forceinline__ void load16_to_lds(const bf16* g, bf16* l) {
    __builtin_amdgcn_global_load_lds((const __attribute__((address_space(1))) void*)g,
                                     (__attribute__((address_space(3))) void*)l,
                                     16, 0, 0);
}

__device__ __forceinline__ int packbf2(float a, float b) {
    bf16x2 v; v[0] = (bf16)a; v[1] = (bf16)b;
    return __builtin_bit_cast(int, v);
}

// ---------------------------------------------------------------------------
// NT GEMM: C[m,n] = sum_k A[m,k]*B[n,k]. 128x128 tile, mega-step BK=64 built
// from TWO verified BK=32 sub-tiles (R14), double-buffered (R12). Loop:
// barrier (drains DMA(i), retires reads of buf[i^1]) -> issue 8 DMAs for
// both slices of step i+1 into buf[i^1] -> compute slice 0, slice 1 of
// buf[i]. 16 barriers per K=1024.
// R15: N is the FAST grid axis (m0 = blockIdx.y) — consecutive blocks share
// the A-panel (256KB, L2-resident) and stream the small B operand.
// CMODE 1: QKV epilogue (Q,K->qk; V->vT transposed, MASKED; bias).
// CMODE 2: f32 C + bias (output projection).
// ---------------------------------------------------------------------------
template <int CMODE>
__global__ __launch_bounds__(256, 2)
void gemm_nt(const bf16* __restrict__ A, const bf16* __restrict__ Bm,
             void* __restrict__ Cv, bf16* __restrict__ vT,
             const float* __restrict__ bias, const int* __restrict__ gmask,
             int K, int lda, int ldb, int ldc)
{
    __shared__ alignas(16) bf16 As[2][2][128 * 32];
    __shared__ alignas(16) bf16 Bs[2][2][128 * 32];

    const int m0 = blockIdx.y * 128;   // R15: swapped (M on slow axis)
    const int n0 = blockIdx.x * 128;   // R15: swapped (N on fast axis)
    const int t    = threadIdx.x;
    const int lane = t & 63;
    const int wv   = t >> 6;
    const int mw   = (wv >> 1) * 64;
    const int nw   = (wv & 1) * 64;

    const int r1 = t >> 2;
    const int c1 = ((t & 3) - (r1 >> 1)) & 3;
    const int r2 = r1 + 64;
    const int c2 = ((t & 3) - (r2 >> 1)) & 3;

    const bf16* ga1 = A  + (long)(m0 + r1) * lda + c1 * 8;
    const bf16* ga2 = A  + (long)(m0 + r2) * lda + c2 * 8;
    const bf16* gb1 = Bm + (long)(n0 + r1) * ldb + c1 * 8;
    const bf16* gb2 = Bm + (long)(n0 + r2) * ldb + c2 * 8;

    const int fr = lane & 15;
    const int fq = lane >> 4;
    int aoff[4], boff[4];
#pragma unroll
    for (int i = 0; i < 4; ++i) {
        int Ra = mw + i * 16 + fr;
        aoff[i] = (Ra * 4 + ((fq + (Ra >> 1)) & 3)) * 8;
        int Rb = nw + i * 16 + fr;
        boff[i] = (Rb * 4 + ((fq + (Rb >> 1)) & 3)) * 8;
    }

    const f32x4 zero4 = {0.f, 0.f, 0.f, 0.f};
    f32x4 acc[4][4];
#pragma unroll
    for (int i = 0; i < 4; ++i)
#pragma unroll
        for (int j = 0; j < 4; ++j) acc[i][j] = zero4;

    // prologue: stage both 32-slices of mega-step 0 into buffer 0
    load16_to_lds(ga1,      &As[0][0][t * 8]);
    load16_to_lds(ga1 + 32, &As[0][1][t * 8]);
    load16_to_lds(ga2,      &As[0][0][(256 + t) * 8]);
    load16_to_lds(ga2 + 32, &As[0][1][(256 + t) * 8]);
    load16_to_lds(gb1,      &Bs[0][0][t * 8]);
    load16_to_lds(gb1 + 32, &Bs[0][1][t * 8]);
    load16_to_lds(gb2,      &Bs[0][0][(256 + t) * 8]);
    load16_to_lds(gb2 + 32, &Bs[0][1][(256 + t) * 8]);

    for (int k0 = 0; k0 < K; k0 += 64) {
        const int cur = (k0 >> 6) & 1;
        __syncthreads();   // drains DMA(cur); retires reads of buf[cur^1]
        if (k0 + 64 < K) {
            ga1 += 64; ga2 += 64; gb1 += 64; gb2 += 64;
            load16_to_lds(ga1,      &As[cur ^ 1][0][t * 8]);
            load16_to_lds(ga1 + 32, &As[cur ^ 1][1][t * 8]);
            load16_to_lds(ga2,      &As[cur ^ 1][0][(256 + t) * 8]);
            load16_to_lds(ga2 + 32, &As[cur ^ 1][1][(256 + t) * 8]);
            load16_to_lds(gb1,      &Bs[cur ^ 1][0][t * 8]);
            load16_to_lds(gb1 + 32, &Bs[cur ^ 1][1][t * 8]);
            load16_to_lds(gb2,      &Bs[cur ^ 1][0][(256 + t) * 8]);
            load16_to_lds(gb2 + 32, &Bs[cur ^ 1][1][(256 + t) * 8]);
        }
#pragma unroll
        for (int s = 0; s < 2; ++s) {
            bf16x8 af[4], bfr[4];
#pragma unroll
            for (int i = 0; i < 4; ++i) af[i]  = *(const bf16x8*)&As[cur][s][aoff[i]];
#pragma unroll
            for (int j = 0; j < 4; ++j) bfr[j] = *(const bf16x8*)&Bs[cur][s][boff[j]];
#pragma unroll
            for (int i = 0; i < 4; ++i)
#pragma unroll
                for (int j = 0; j < 4; ++j)
                    acc[i][j] = __builtin_amdgcn_mfma_f32_16x16x32_bf16(af[i], bfr[j], acc[i][j], 0, 0, 0);
        }
    }

    float bval = 0.f;
    if (CMODE == 1 || CMODE == 2) bval = bias[0];

#pragma unroll
    for (int i = 0; i < 4; ++i) {
        const int row0 = m0 + mw + i * 16 + fq * 4;
#pragma unroll
        for (int j = 0; j < 4; ++j) {
            const int col = n0 + nw + j * 16 + fr;
            if (CMODE == 2) {
                float* C = (float*)Cv;
#pragma unroll
                for (int r = 0; r < 4; ++r)
                    C[(long)(row0 + r) * ldc + col] = acc[i][j][r] + bval;
            } else {  // CMODE 1: QKV
                bf16* C = (bf16*)Cv;
                if (col < 2048) {
                    const float badd = (col < 1024) ? bval * QK_SCALE : bval;
#pragma unroll
                    for (int r = 0; r < 4; ++r)
                        C[(long)(row0 + r) * ldc + col] = (bf16)(acc[i][j][r] + badd);
                } else {  // V -> vT[(b*8+h)*128+dk][s], masked (mask trick)
                    const int vcol = col - 2048;
                    const int h  = vcol >> 7;
                    const int dk = vcol & 127;
                    const int b  = row0 >> 11;
                    const int s  = row0 & 2047;
                    i32x4 m4 = *(const i32x4*)(gmask + b * 2048 + s);
                    bf16x4 pack;
#pragma unroll
                    for (int r = 0; r < 4; ++r)
                        pack[r] = (bf16)((acc[i][j][r] + bval) * (float)m4[r]);
                    *(bf16x4*)&vT[((long)((b * 8 + h) * 128 + dk)) * 2048 + s] = pack;
                }
            }
        }
    }
}

// ---------------------------------------------------------------------------
// Flash v2 (R8-exact body) + R13 XCD-affinity block swizzle (kept: FETCH
// 139->24.7MB, dur 91->88.8us). Block = 128 Q-rows x one (b,h); wave = 32
// Q-rows. 16 key-tiles.
// qk: [b*2048+s][h*128+k]  Q (cols 0..1023, pre-scaled) | K (cols 1024..2047)
// vT: [(b*8+h)*128+dk][s]  (masked rows zeroed)
// mbf: bf16 mask [b][2048] in {0,1}
// mh:  [b*2048+s][(7-h)*128+dk]  (head reversal folded)
// LDS: Kh/Vh 32KB each, 16B-chunk swizzle pos=(chunk+row)&15.
// Per tile: QK^T (S^T, A=K B=Q) -> exp -> in-reg half-exchange -> P A-frags;
// l += P*maskfrag MFMA; O += P*V MFMA. 2 barriers/tile, DMA prefetch between.
// s_setprio(1) around the MFMA clusters (T5).
// ---------------------------------------------------------------------------
__global__ __launch_bounds__(256, 2)
void flash2(const bf16* __restrict__ qk, const bf16* __restrict__ vT,
            const bf16* __restrict__ mbf, bf16* __restrict__ mh)
{
    __shared__ alignas(16) bf16 Kh[128 * 128];
    __shared__ alignas(16) bf16 Vh[128 * 128];

    // R13: XCD-affinity remap. Dispatch-linear id (x-fast) round-robins
    // XCDs as id%8. Map so XCD x owns bh in {4x..4x+3}, all 16 qt each:
    // per-XCD K/V working set = 4 x 1MB = 4MB = one L2.
    const int lid = blockIdx.y * gridDim.x + blockIdx.x;
    const int qt = lid >> 5;
    const int bh = (lid & 7) * 4 + ((lid >> 3) & 3);
    const int b = bh >> 3, h = bh & 7;
    const int q0 = qt * 128;
    const int t = threadIdx.x, lane = t & 63, wv = t >> 6;
    const int l31 = lane & 31;
    const int hl  = lane >> 5;

    const bf16* Qb = qk + ((long)(b * 2048 + q0)) * 2048 + h * 128;
    const bf16* Kb = qk + (long)b * 2048 * 2048 + 1024 + h * 128;
    const bf16* Vb = vT + (long)bh * 128 * 2048;
    const bf16* mrow = mbf + b * 2048;

    // staging map (same as validated R2): thread t fills 16B slot t each round
    const int r0 = t >> 4;
    const int co = (((t & 15) - r0) & 15) * 8;   // logical chunk offset (elems)
    bf16* ldK = &Kh[t * 8];
    bf16* ldV = &Vh[t * 8];

    // ---- stage Q into Kh, read Q B-frags ----
    {
        const bf16* s = Qb + (long)r0 * 2048 + co;
#pragma unroll
        for (int rnd = 0; rnd < 8; ++rnd)
            load16_to_lds(s + (long)rnd * 16 * 2048, ldK + rnd * 2048);
    }
    __syncthreads();
    bf16x8 qf[8];
#pragma unroll
    for (int kc = 0; kc < 8; ++kc) {
        int row = wv * 32 + l31;
        int pos = ((kc * 2 + hl) + row) & 15;
        qf[kc] = *(const bf16x8*)&Kh[row * 128 + pos * 8];
    }
    __syncthreads();   // qf reads done; Kh free

    // prologue DMA: K(0), V(0)
    {
        const bf16* sk = Kb + (long)r0 * 2048 + co;
        const bf16* sv = Vb + (long)r0 * 2048 + co;
#pragma unroll
        for (int rnd = 0; rnd < 8; ++rnd) {
            load16_to_lds(sk + (long)rnd * 16 * 2048, ldK + rnd * 2048);
            load16_to_lds(sv + (long)rnd * 16 * 2048, ldV + rnd * 2048);
        }
    }
    __syncthreads();   // K(0), V(0) ready

    f32x16 O4[4], lac;
#pragma unroll
    for (int r = 0; r < 16; ++r) {
        lac[r] = 0.f;
#pragma unroll
        for (int nt = 0; nt < 4; ++nt) O4[nt][r] = 0.f;
    }

    for (int t0 = 0; t0 < 2048; t0 += 128) {
        // ---- S^T = K.Q^T per m-tile; exp; in-register P-frag build ----
        bf16x8 pf[8];
#pragma unroll
        for (int mt = 0; mt < 4; ++mt) {
            f32x16 S;
#pragma unroll
            for (int r = 0; r < 16; ++r) S[r] = 0.f;
            __builtin_amdgcn_s_setprio(1);
#pragma unroll
            for (int kc = 0; kc < 8; ++kc) {
                int row = mt * 32 + l31;
                int pos = ((kc * 2 + hl) + row) & 15;
                bf16x8 kf = *(const bf16x8*)&Kh[row * 128 + pos * 8];
                S = __builtin_amdgcn_mfma_f32_32x32x16_bf16(kf, qf[kc], S, 0, 0, 0);
            }
            __builtin_amdgcn_s_setprio(0);
            // exp (no max-shift: scores bounded) and pack to bf16 dwords
            int ownd[4][2];
#pragma unroll
            for (int g = 0; g < 4; ++g) {
                float e0 = __expf(S[g * 4 + 0]);
                float e1 = __expf(S[g * 4 + 1]);
                float e2 = __expf(S[g * 4 + 2]);
                float e3 = __expf(S[g * 4 + 3]);
                ownd[g][0] = packbf2(e0, e1);
                ownd[g][1] = packbf2(e2, e3);
            }
            // exchange 4-key halves with lane^32
            int rcv[4][2];
#pragma unroll
            for (int g = 0; g < 4; ++g) {
                rcv[g][0] = __shfl_xor(ownd[g][0], 32);
                rcv[g][1] = __shfl_xor(ownd[g][1], 32);
            }
            // assemble A-frags: frag kc=2mt+kk holds keys kc*16+hl*8+{0..7}
#pragma unroll
            for (int kk = 0; kk < 2; ++kk) {
                i32x4 w;
                w[0] = hl ? rcv[2 * kk + 1][0] : ownd[2 * kk][0];
                w[1] = hl ? rcv[2 * kk + 1][1] : ownd[2 * kk][1];
                w[2] = hl ? ownd[2 * kk + 1][0] : rcv[2 * kk][0];
                w[3] = hl ? ownd[2 * kk + 1][1] : rcv[2 * kk][1];
                pf[mt * 2 + kk] = __builtin_bit_cast(bf16x8, w);
            }
        }

        __syncthreads();   // b1: all QK reads of Kh done; V(t0) drained

        // mask frags first (so l-MFMA's vmcnt wait doesn't drain the K prefetch)
        bf16x8 mf[8];
#pragma unroll
        for (int kc = 0; kc < 8; ++kc)
            mf[kc] = *(const bf16x8*)(mrow + t0 + kc * 16 + hl * 8);

        // prefetch K(t0+1) into Kh (hidden under l-MFMA + PV)
        if (t0 < 2048 - 128) {
            const bf16* sk = Kb + (long)(t0 + 128 + r0) * 2048 + co;
#pragma unroll
            for (int rnd = 0; rnd < 8; ++rnd)
                load16_to_lds(sk + (long)rnd * 16 * 2048, ldK + rnd * 2048);
        }

        // l += P . mask   (D rows = qrow, same layout as O)
        __builtin_amdgcn_s_setprio(1);
#pragma unroll
        for (int kc = 0; kc < 8; ++kc)
            lac = __builtin_amdgcn_mfma_f32_32x32x16_bf16(pf[kc], mf[kc], lac, 0, 0, 0);

        // O += P . V^T-rows
#pragma unroll
        for (int kc = 0; kc < 8; ++kc) {
#pragma unroll
            for (int nt = 0; nt < 4; ++nt) {
                int row = nt * 32 + l31;
                int pos = ((kc * 2 + hl) + row) & 15;
                bf16x8 vf = *(const bf16x8*)&Vh[row * 128 + pos * 8];
                O4[nt] = __builtin_amdgcn_mfma_f32_32x32x16_bf16(pf[kc], vf, O4[nt], 0, 0, 0);
            }
        }
        __builtin_amdgcn_s_setprio(0);

        __syncthreads();   // b2: Vh free; K(t0+1) drained

        // prefetch V(t0+1) into Vh (drained at next b1)
        if (t0 < 2048 - 128) {
            const bf16* sv = Vb + (long)r0 * 2048 + (t0 + 128) + co;
#pragma unroll
            for (int rnd = 0; rnd < 8; ++rnd)
                load16_to_lds(sv + (long)rnd * 16 * 2048, ldV + rnd * 2048);
        }
    }

    // ---- epilogue: O /= l, store with head reversal ----
    float invl[16];
#pragma unroll
    for (int r = 0; r < 16; ++r) invl[r] = 1.0f / lac[r];
    bf16* outb = mh + ((long)(b * 2048 + q0 + wv * 32)) * 1024 + (7 - h) * 128;
#pragma unroll
    for (int nt = 0; nt < 4; ++nt)
#pragma unroll
        for (int r = 0; r < 16; ++r) {
            int row = (r & 3) + 8 * (r >> 2) + 4 * hl;
            outb[(long)row * 1024 + nt * 32 + l31] = (bf16)(O4[nt][r] * invl[r]);
        }
}

// ---------------------------------------------------------------------------
__global__ __launch_bounds__(256)
void pack_f32_bf16(const float* __restrict__ src, bf16* __restrict__ dst, int n)
{
    int i = (blockIdx.x * 256 + threadIdx.x) * 4;
    if (i >= n) return;
    float4 f = *(const float4*)(src + i);
    bf16x4 o;
    o[0] = (bf16)f.x; o[1] = (bf16)f.y; o[2] = (bf16)f.z; o[3] = (bf16)f.w;
    *(bf16x4*)(dst + i) = o;
}

__global__ __launch_bounds__(256)
void pack_mask(const int* __restrict__ mask, bf16* __restrict__ mbf, int n)
{
    int i = (blockIdx.x * 256 + threadIdx.x) * 4;
    if (i >= n) return;
    i32x4 m = *(const i32x4*)(mask + i);
    bf16x4 o;
#pragma unroll
    for (int r = 0; r < 4; ++r) o[r] = (bf16)(float)m[r];
    *(bf16x4*)(mbf + i) = o;
}

__global__ __launch_bounds__(256)
void pack_wt(const float* __restrict__ Wq, const float* __restrict__ Wk,
             const float* __restrict__ Wv, bf16* __restrict__ wt)
{
    __shared__ float tile[64][65];
    const int which = blockIdx.z;
    const float* W = (which == 0) ? Wq : (which == 1) ? Wk : Wv;
    const float scale = (which == 0) ? QK_SCALE : 1.0f;
    const int h  = blockIdx.y;
    const int d0 = (blockIdx.x >> 1) * 64;
    const int k0 = (blockIdx.x & 1) * 64;
    const float* Wh = W + (long)h * 1024 * 128;
#pragma unroll
    for (int it = 0; it < 16; ++it) {
        int e = it * 256 + threadIdx.x;
        int r = e >> 6, c = e & 63;
        tile[r][c] = Wh[(long)(d0 + r) * 128 + (k0 + c)];
    }
    __syncthreads();
#pragma unroll
    for (int it = 0; it < 16; ++it) {
        int e = it * 256 + threadIdx.x;
        int rk = e >> 6, cd = e & 63;
        int n = which * 1024 + h * 128 + k0 + rk;
        wt[(long)n * 1024 + d0 + cd] = (bf16)(tile[cd][rk] * scale);
    }
}

// ---------------------------------------------------------------------------
extern "C" void kernel_launch(void* const* d_in, const int* in_sizes, int n_in,
                              void* d_out, int out_size, void* d_ws, size_t ws_size,
                              hipStream_t stream)
{
    const float* x    = (const float*)d_in[0];
    const int*   mask = (const int*)d_in[1];
    const float* Wq   = (const float*)d_in[2];
    const float* Wk   = (const float*)d_in[3];
    const float* Wv   = (const float*)d_in[4];
    const float* Wo   = (const float*)d_in[5];
    const float* bias = (const float*)d_in[6];
    float* out = (float*)d_out;

    char* w = (char*)d_ws;
    bf16* xb  = (bf16*)w; w += (size_t)8192 * 1024 * 2;        // 16 MB
    bf16* wt  = (bf16*)w; w += (size_t)3072 * 1024 * 2;        //  6 MB
    bf16* wob = (bf16*)w; w += (size_t)1024 * 1024 * 2;        //  2 MB
    bf16* qk  = (bf16*)w; w += (size_t)8192 * 2048 * 2;        // 32 MB
    bf16* vT  = (bf16*)w; w += (size_t)32 * 128 * 2048 * 2;    // 16 MB
    bf16* mh  = (bf16*)w; w += (size_t)8192 * 1024 * 2;        // 16 MB
    bf16* mbf = (bf16*)w; w += (size_t)4 * 2048 * 2;           // 16 KB

    pack_f32_bf16<<<8192, 256, 0, stream>>>(x, xb, 8192 * 1024);
    pack_f32_bf16<<<1024, 256, 0, stream>>>(Wo, wob, 1024 * 1024);
    pack_mask<<<8, 256, 0, stream>>>(mask, mbf, 8192);
    pack_wt<<<dim3(32, 8, 3), 256, 0, stream>>>(Wq, Wk, Wv, wt);

    // QKV projection: M=8192 N=3072 K=1024 (V masked in epilogue)
    // R15: grid (N/128, M/128) — N fast
    gemm_nt<1><<<dim3(24, 64), 256, 0, stream>>>(
        xb, wt, qk, vT, bias, mask, 1024, 1024, 1024, 2048);

    // fused attention
    flash2<<<dim3(16, 32), 256, 0, stream>>>(qk, vT, mbf, mh);

    // out = mh @ Wo^T + b: M=8192 N=1024 K=1024, fp32 out
    // R15: grid (N/128, M/128) — N fast
    gemm_nt<2><<<dim3(8, 64), 256, 0, stream>>>(
        mh, wob, out, nullptr, bias, nullptr, 1024, 1024, 1024, 1024);
}

// Round 13
// 258.300 us; speedup vs baseline: 1.0619x; 1.0619x over previous
//
#include <hip/hip_runtime.h>
#include <math.h>

// SelfAttention fused pipeline, MI355X gfx950.
// B=4 S=2048 D=1024 H=8 DK=128.
// R3: flash v2 — S^T orientation, 32x32x16 MFMA, exp-only softmax, masked-V
// + l via mask-MFMA, in-reg P transpose, K/V LDS staging + DMA prefetch.
// R4: T5 s_setprio around flash2 MFMA clusters (kept).
// R7/R9/R10 FAILED: reg caps spill; novel LDS layouts bank-conflict.
// R12: gemm dbuf +1.3us. R13: flash2 XCD-affinity swizzle (FETCH 139->25MB,
// -2.3us; kept). R14: gemm mega-step BK=64 (dup'd BK=32 slices) -9.8us ->
// 266.0us session best. R15 FAILED (+8.3us): N-fast grid swap — A-panel
// replicated into all 8 XCD L2s by round-robin dispatch while B(6MB) still
// misses the 4MB per-XCD L2; axis family closed (both orders measured).
// R16: revert R15 (gemm grids back to R14-exact) + fuse the 4 pack kernels
// into ONE pack_all dispatch (block-range branch; bodies byte-identical).
// Removes 3 dispatch boundaries; tiny packs co-schedule in x-pack's tail.
// Decisive for the ~48us sum-vs-total gap: flat result => gap is per-kernel
// ramp (practical plateau).

typedef __bf16 bf16;
typedef __bf16 bf16x2 __attribute__((ext_vector_type(2)));
typedef __bf16 bf16x4 __attribute__((ext_vector_type(4)));
typedef __bf16 bf16x8 __attribute__((ext_vector_type(8)));
typedef float  f32x4  __attribute__((ext_vector_type(4)));
typedef float  f32x16 __attribute__((ext_vector_type(16)));
typedef int    i32x4  __attribute__((ext_vector_type(4)));

constexpr float QK_SCALE = 0.08838834764831845f;  // 1/sqrt(128)

__device__ __forceinline__ void load16_to_lds(const bf16* g, bf16* l) {
    __builtin_amdgcn_global_load_lds((const __attribute__((address_space(1))) void*)g,
                                     (__attribute__((address_space(3))) void*)l,
                                     16, 0, 0);
}

__device__ __forceinline__ int packbf2(float a, float b) {
    bf16x2 v; v[0] = (bf16)a; v[1] = (bf16)b;
    return __builtin_bit_cast(int, v);
}

// ---------------------------------------------------------------------------
// NT GEMM: C[m,n] = sum_k A[m,k]*B[n,k]. 128x128 tile, mega-step BK=64 built
// from TWO verified BK=32 sub-tiles (R14), double-buffered (R12). Loop:
// barrier (drains DMA(i), retires reads of buf[i^1]) -> issue 8 DMAs for
// both slices of step i+1 into buf[i^1] -> compute slice 0, slice 1 of
// buf[i]. 16 barriers per K=1024. Grid: x=M fast (R14-verified order).
// CMODE 1: QKV epilogue (Q,K->qk; V->vT transposed, MASKED; bias).
// CMODE 2: f32 C + bias (output projection).
// ---------------------------------------------------------------------------
template <int CMODE>
__global__ __launch_bounds__(256, 2)
void gemm_nt(const bf16* __restrict__ A, const bf16* __restrict__ Bm,
             void* __restrict__ Cv, bf16* __restrict__ vT,
             const float* __restrict__ bias, const int* __restrict__ gmask,
             int K, int lda, int ldb, int ldc)
{
    __shared__ alignas(16) bf16 As[2][2][128 * 32];
    __shared__ alignas(16) bf16 Bs[2][2][128 * 32];

    const int m0 = blockIdx.x * 128;
    const int n0 = blockIdx.y * 128;
    const int t    = threadIdx.x;
    const int lane = t & 63;
    const int wv   = t >> 6;
    const int mw   = (wv >> 1) * 64;
    const int nw   = (wv & 1) * 64;

    const int r1 = t >> 2;
    const int c1 = ((t & 3) - (r1 >> 1)) & 3;
    const int r2 = r1 + 64;
    const int c2 = ((t & 3) - (r2 >> 1)) & 3;

    const bf16* ga1 = A  + (long)(m0 + r1) * lda + c1 * 8;
    const bf16* ga2 = A  + (long)(m0 + r2) * lda + c2 * 8;
    const bf16* gb1 = Bm + (long)(n0 + r1) * ldb + c1 * 8;
    const bf16* gb2 = Bm + (long)(n0 + r2) * ldb + c2 * 8;

    const int fr = lane & 15;
    const int fq = lane >> 4;
    int aoff[4], boff[4];
#pragma unroll
    for (int i = 0; i < 4; ++i) {
        int Ra = mw + i * 16 + fr;
        aoff[i] = (Ra * 4 + ((fq + (Ra >> 1)) & 3)) * 8;
        int Rb = nw + i * 16 + fr;
        boff[i] = (Rb * 4 + ((fq + (Rb >> 1)) & 3)) * 8;
    }

    const f32x4 zero4 = {0.f, 0.f, 0.f, 0.f};
    f32x4 acc[4][4];
#pragma unroll
    for (int i = 0; i < 4; ++i)
#pragma unroll
        for (int j = 0; j < 4; ++j) acc[i][j] = zero4;

    // prologue: stage both 32-slices of mega-step 0 into buffer 0
    load16_to_lds(ga1,      &As[0][0][t * 8]);
    load16_to_lds(ga1 + 32, &As[0][1][t * 8]);
    load16_to_lds(ga2,      &As[0][0][(256 + t) * 8]);
    load16_to_lds(ga2 + 32, &As[0][1][(256 + t) * 8]);
    load16_to_lds(gb1,      &Bs[0][0][t * 8]);
    load16_to_lds(gb1 + 32, &Bs[0][1][t * 8]);
    load16_to_lds(gb2,      &Bs[0][0][(256 + t) * 8]);
    load16_to_lds(gb2 + 32, &Bs[0][1][(256 + t) * 8]);

    for (int k0 = 0; k0 < K; k0 += 64) {
        const int cur = (k0 >> 6) & 1;
        __syncthreads();   // drains DMA(cur); retires reads of buf[cur^1]
        if (k0 + 64 < K) {
            ga1 += 64; ga2 += 64; gb1 += 64; gb2 += 64;
            load16_to_lds(ga1,      &As[cur ^ 1][0][t * 8]);
            load16_to_lds(ga1 + 32, &As[cur ^ 1][1][t * 8]);
            load16_to_lds(ga2,      &As[cur ^ 1][0][(256 + t) * 8]);
            load16_to_lds(ga2 + 32, &As[cur ^ 1][1][(256 + t) * 8]);
            load16_to_lds(gb1,      &Bs[cur ^ 1][0][t * 8]);
            load16_to_lds(gb1 + 32, &Bs[cur ^ 1][1][t * 8]);
            load16_to_lds(gb2,      &Bs[cur ^ 1][0][(256 + t) * 8]);
            load16_to_lds(gb2 + 32, &Bs[cur ^ 1][1][(256 + t) * 8]);
        }
#pragma unroll
        for (int s = 0; s < 2; ++s) {
            bf16x8 af[4], bfr[4];
#pragma unroll
            for (int i = 0; i < 4; ++i) af[i]  = *(const bf16x8*)&As[cur][s][aoff[i]];
#pragma unroll
            for (int j = 0; j < 4; ++j) bfr[j] = *(const bf16x8*)&Bs[cur][s][boff[j]];
#pragma unroll
            for (int i = 0; i < 4; ++i)
#pragma unroll
                for (int j = 0; j < 4; ++j)
                    acc[i][j] = __builtin_amdgcn_mfma_f32_16x16x32_bf16(af[i], bfr[j], acc[i][j], 0, 0, 0);
        }
    }

    float bval = 0.f;
    if (CMODE == 1 || CMODE == 2) bval = bias[0];

#pragma unroll
    for (int i = 0; i < 4; ++i) {
        const int row0 = m0 + mw + i * 16 + fq * 4;
#pragma unroll
        for (int j = 0; j < 4; ++j) {
            const int col = n0 + nw + j * 16 + fr;
            if (CMODE == 2) {
                float* C = (float*)Cv;
#pragma unroll
                for (int r = 0; r < 4; ++r)
                    C[(long)(row0 + r) * ldc + col] = acc[i][j][r] + bval;
            } else {  // CMODE 1: QKV
                bf16* C = (bf16*)Cv;
                if (col < 2048) {
                    const float badd = (col < 1024) ? bval * QK_SCALE : bval;
#pragma unroll
                    for (int r = 0; r < 4; ++r)
                        C[(long)(row0 + r) * ldc + col] = (bf16)(acc[i][j][r] + badd);
                } else {  // V -> vT[(b*8+h)*128+dk][s], masked (mask trick)
                    const int vcol = col - 2048;
                    const int h  = vcol >> 7;
                    const int dk = vcol & 127;
                    const int b  = row0 >> 11;
                    const int s  = row0 & 2047;
                    i32x4 m4 = *(const i32x4*)(gmask + b * 2048 + s);
                    bf16x4 pack;
#pragma unroll
                    for (int r = 0; r < 4; ++r)
                        pack[r] = (bf16)((acc[i][j][r] + bval) * (float)m4[r]);
                    *(bf16x4*)&vT[((long)((b * 8 + h) * 128 + dk)) * 2048 + s] = pack;
                }
            }
        }
    }
}

// ---------------------------------------------------------------------------
// Flash v2 (R8-exact body) + R13 XCD-affinity block swizzle (kept: FETCH
// 139->24.7MB). Block = 128 Q-rows x one (b,h); wave = 32 Q-rows.
// LDS: Kh/Vh 32KB each, 16B-chunk swizzle pos=(chunk+row)&15.
// Per tile: QK^T (S^T, A=K B=Q) -> exp -> in-reg half-exchange -> P A-frags;
// l += P*maskfrag MFMA; O += P*V MFMA. 2 barriers/tile, DMA prefetch between.
// s_setprio(1) around the MFMA clusters (T5).
// ---------------------------------------------------------------------------
__global__ __launch_bounds__(256, 2)
void flash2(const bf16* __restrict__ qk, const bf16* __restrict__ vT,
            const bf16* __restrict__ mbf, bf16* __restrict__ mh)
{
    __shared__ alignas(16) bf16 Kh[128 * 128];
    __shared__ alignas(16) bf16 Vh[128 * 128];

    // R13: XCD-affinity remap. XCD x owns bh in {4x..4x+3}, all 16 qt each:
    // per-XCD K/V working set = 4 x 1MB = 4MB = one L2.
    const int lid = blockIdx.y * gridDim.x + blockIdx.x;
    const int qt = lid >> 5;
    const int bh = (lid & 7) * 4 + ((lid >> 3) & 3);
    const int b = bh >> 3, h = bh & 7;
    const int q0 = qt * 128;
    const int t = threadIdx.x, lane = t & 63, wv = t >> 6;
    const int l31 = lane & 31;
    const int hl  = lane >> 5;

    const bf16* Qb = qk + ((long)(b * 2048 + q0)) * 2048 + h * 128;
    const bf16* Kb = qk + (long)b * 2048 * 2048 + 1024 + h * 128;
    const bf16* Vb = vT + (long)bh * 128 * 2048;
    const bf16* mrow = mbf + b * 2048;

    // staging map (validated R2): thread t fills 16B slot t each round
    const int r0 = t >> 4;
    const int co = (((t & 15) - r0) & 15) * 8;   // logical chunk offset (elems)
    bf16* ldK = &Kh[t * 8];
    bf16* ldV = &Vh[t * 8];

    // ---- stage Q into Kh, read Q B-frags ----
    {
        const bf16* s = Qb + (long)r0 * 2048 + co;
#pragma unroll
        for (int rnd = 0; rnd < 8; ++rnd)
            load16_to_lds(s + (long)rnd * 16 * 2048, ldK + rnd * 2048);
    }
    __syncthreads();
    bf16x8 qf[8];
#pragma unroll
    for (int kc = 0; kc < 8; ++kc) {
        int row = wv * 32 + l31;
        int pos = ((kc * 2 + hl) + row) & 15;
        qf[kc] = *(const bf16x8*)&Kh[row * 128 + pos * 8];
    }
    __syncthreads();   // qf reads done; Kh free

    // prologue DMA: K(0), V(0)
    {
        const bf16* sk = Kb + (long)r0 * 2048 + co;
        const bf16* sv = Vb + (long)r0 * 2048 + co;
#pragma unroll
        for (int rnd = 0; rnd < 8; ++rnd) {
            load16_to_lds(sk + (long)rnd * 16 * 2048, ldK + rnd * 2048);
            load16_to_lds(sv + (long)rnd * 16 * 2048, ldV + rnd * 2048);
        }
    }
    __syncthreads();   // K(0), V(0) ready

    f32x16 O4[4], lac;
#pragma unroll
    for (int r = 0; r < 16; ++r) {
        lac[r] = 0.f;
#pragma unroll
        for (int nt = 0; nt < 4; ++nt) O4[nt][r] = 0.f;
    }

    for (int t0 = 0; t0 < 2048; t0 += 128) {
        // ---- S^T = K.Q^T per m-tile; exp; in-register P-frag build ----
        bf16x8 pf[8];
#pragma unroll
        for (int mt = 0; mt < 4; ++mt) {
            f32x16 S;
#pragma unroll
            for (int r = 0; r < 16; ++r) S[r] = 0.f;
            __builtin_amdgcn_s_setprio(1);
#pragma unroll
            for (int kc = 0; kc < 8; ++kc) {
                int row = mt * 32 + l31;
                int pos = ((kc * 2 + hl) + row) & 15;
                bf16x8 kf = *(const bf16x8*)&Kh[row * 128 + pos * 8];
                S = __builtin_amdgcn_mfma_f32_32x32x16_bf16(kf, qf[kc], S, 0, 0, 0);
            }
            __builtin_amdgcn_s_setprio(0);
            // exp (no max-shift: scores bounded) and pack to bf16 dwords
            int ownd[4][2];
#pragma unroll
            for (int g = 0; g < 4; ++g) {
                float e0 = __expf(S[g * 4 + 0]);
                float e1 = __expf(S[g * 4 + 1]);
                float e2 = __expf(S[g * 4 + 2]);
                float e3 = __expf(S[g * 4 + 3]);
                ownd[g][0] = packbf2(e0, e1);
                ownd[g][1] = packbf2(e2, e3);
            }
            // exchange 4-key halves with lane^32
            int rcv[4][2];
#pragma unroll
            for (int g = 0; g < 4; ++g) {
                rcv[g][0] = __shfl_xor(ownd[g][0], 32);
                rcv[g][1] = __shfl_xor(ownd[g][1], 32);
            }
            // assemble A-frags: frag kc=2mt+kk holds keys kc*16+hl*8+{0..7}
#pragma unroll
            for (int kk = 0; kk < 2; ++kk) {
                i32x4 w;
                w[0] = hl ? rcv[2 * kk + 1][0] : ownd[2 * kk][0];
                w[1] = hl ? rcv[2 * kk + 1][1] : ownd[2 * kk][1];
                w[2] = hl ? ownd[2 * kk + 1][0] : rcv[2 * kk][0];
                w[3] = hl ? ownd[2 * kk + 1][1] : rcv[2 * kk][1];
                pf[mt * 2 + kk] = __builtin_bit_cast(bf16x8, w);
            }
        }

        __syncthreads();   // b1: all QK reads of Kh done; V(t0) drained

        // mask frags first (so l-MFMA's vmcnt wait doesn't drain the K prefetch)
        bf16x8 mf[8];
#pragma unroll
        for (int kc = 0; kc < 8; ++kc)
            mf[kc] = *(const bf16x8*)(mrow + t0 + kc * 16 + hl * 8);

        // prefetch K(t0+1) into Kh (hidden under l-MFMA + PV)
        if (t0 < 2048 - 128) {
            const bf16* sk = Kb + (long)(t0 + 128 + r0) * 2048 + co;
#pragma unroll
            for (int rnd = 0; rnd < 8; ++rnd)
                load16_to_lds(sk + (long)rnd * 16 * 2048, ldK + rnd * 2048);
        }

        // l += P . mask   (D rows = qrow, same layout as O)
        __builtin_amdgcn_s_setprio(1);
#pragma unroll
        for (int kc = 0; kc < 8; ++kc)
            lac = __builtin_amdgcn_mfma_f32_32x32x16_bf16(pf[kc], mf[kc], lac, 0, 0, 0);

        // O += P . V^T-rows
#pragma unroll
        for (int kc = 0; kc < 8; ++kc) {
#pragma unroll
            for (int nt = 0; nt < 4; ++nt) {
                int row = nt * 32 + l31;
                int pos = ((kc * 2 + hl) + row) & 15;
                bf16x8 vf = *(const bf16x8*)&Vh[row * 128 + pos * 8];
                O4[nt] = __builtin_amdgcn_mfma_f32_32x32x16_bf16(pf[kc], vf, O4[nt], 0, 0, 0);
            }
        }
        __builtin_amdgcn_s_setprio(0);

        __syncthreads();   // b2: Vh free; K(t0+1) drained

        // prefetch V(t0+1) into Vh (drained at next b1)
        if (t0 < 2048 - 128) {
            const bf16* sv = Vb + (long)r0 * 2048 + (t0 + 128) + co;
#pragma unroll
            for (int rnd = 0; rnd < 8; ++rnd)
                load16_to_lds(sv + (long)rnd * 16 * 2048, ldV + rnd * 2048);
        }
    }

    // ---- epilogue: O /= l, store with head reversal ----
    float invl[16];
#pragma unroll
    for (int r = 0; r < 16; ++r) invl[r] = 1.0f / lac[r];
    bf16* outb = mh + ((long)(b * 2048 + q0 + wv * 32)) * 1024 + (7 - h) * 128;
#pragma unroll
    for (int nt = 0; nt < 4; ++nt)
#pragma unroll
        for (int r = 0; r < 16; ++r) {
            int row = (r & 3) + 8 * (r >> 2) + 4 * hl;
            outb[(long)row * 1024 + nt * 32 + l31] = (bf16)(O4[nt][r] * invl[r]);
        }
}

// ---------------------------------------------------------------------------
// R16: all four preprocessing packs fused into ONE dispatch. Block ranges:
// [0,8192)      x f32 -> xb bf16            (8192*1024 elems, 4/thread)
// [8192,9216)   Wo f32 -> wob bf16          (1024*1024 elems)
// [9216,9224)   mask i32 -> mbf bf16        (8192 elems)
// [9224,9992)   Wq/Wk/Wv transpose -> wt    (768 logical blocks, LDS tile)
// Each body is byte-identical to its verified standalone kernel; branches
// are block-uniform (syncthreads in the wt branch is legal).
// ---------------------------------------------------------------------------
__global__ __launch_bounds__(256)
void pack_all(const float* __restrict__ x, bf16* __restrict__ xb,
              const float* __restrict__ Wo, bf16* __restrict__ wob,
              const int* __restrict__ mask, bf16* __restrict__ mbf,
              const float* __restrict__ Wq, const float* __restrict__ Wk,
              const float* __restrict__ Wv, bf16* __restrict__ wt)
{
    __shared__ float tile[64][65];
    const int bid = blockIdx.x;

    if (bid < 8192) {                       // x -> xb
        int i = (bid * 256 + (int)threadIdx.x) * 4;
        float4 f = *(const float4*)(x + i);
        bf16x4 o;
        o[0] = (bf16)f.x; o[1] = (bf16)f.y; o[2] = (bf16)f.z; o[3] = (bf16)f.w;
        *(bf16x4*)(xb + i) = o;
    } else if (bid < 9216) {                // Wo -> wob
        int i = ((bid - 8192) * 256 + (int)threadIdx.x) * 4;
        float4 f = *(const float4*)(Wo + i);
        bf16x4 o;
        o[0] = (bf16)f.x; o[1] = (bf16)f.y; o[2] = (bf16)f.z; o[3] = (bf16)f.w;
        *(bf16x4*)(wob + i) = o;
    } else if (bid < 9224) {                // mask -> mbf
        int i = ((bid - 9216) * 256 + (int)threadIdx.x) * 4;
        i32x4 m = *(const i32x4*)(mask + i);
        bf16x4 o;
#pragma unroll
        for (int r = 0; r < 4; ++r) o[r] = (bf16)(float)m[r];
        *(bf16x4*)(mbf + i) = o;
    } else {                                // Wq/Wk/Wv transpose -> wt
        const int rem   = bid - 9224;       // [0,768)
        const int which = rem >> 8;         // 0..2
        const int h     = (rem >> 5) & 7;   // 0..7
        const int xbk   = rem & 31;         // 0..31
        const float* W = (which == 0) ? Wq : (which == 1) ? Wk : Wv;
        const float scale = (which == 0) ? QK_SCALE : 1.0f;
        const int d0 = (xbk >> 1) * 64;
        const int k0 = (xbk & 1) * 64;
        const float* Wh = W + (long)h * 1024 * 128;
#pragma unroll
        for (int it = 0; it < 16; ++it) {
            int e = it * 256 + (int)threadIdx.x;
            int r = e >> 6, c = e & 63;
            tile[r][c] = Wh[(long)(d0 + r) * 128 + (k0 + c)];
        }
        __syncthreads();
#pragma unroll
        for (int it = 0; it < 16; ++it) {
            int e = it * 256 + (int)threadIdx.x;
            int rk = e >> 6, cd = e & 63;
            int n = which * 1024 + h * 128 + k0 + rk;
            wt[(long)n * 1024 + d0 + cd] = (bf16)(tile[cd][rk] * scale);
        }
    }
}

// ---------------------------------------------------------------------------
extern "C" void kernel_launch(void* const* d_in, const int* in_sizes, int n_in,
                              void* d_out, int out_size, void* d_ws, size_t ws_size,
                              hipStream_t stream)
{
    const float* x    = (const float*)d_in[0];
    const int*   mask = (const int*)d_in[1];
    const float* Wq   = (const float*)d_in[2];
    const float* Wk   = (const float*)d_in[3];
    const float* Wv   = (const float*)d_in[4];
    const float* Wo   = (const float*)d_in[5];
    const float* bias = (const float*)d_in[6];
    float* out = (float*)d_out;

    char* w = (char*)d_ws;
    bf16* xb  = (bf16*)w; w += (size_t)8192 * 1024 * 2;        // 16 MB
    bf16* wt  = (bf16*)w; w += (size_t)3072 * 1024 * 2;        //  6 MB
    bf16* wob = (bf16*)w; w += (size_t)1024 * 1024 * 2;        //  2 MB
    bf16* qk  = (bf16*)w; w += (size_t)8192 * 2048 * 2;        // 32 MB
    bf16* vT  = (bf16*)w; w += (size_t)32 * 128 * 2048 * 2;    // 16 MB
    bf16* mh  = (bf16*)w; w += (size_t)8192 * 1024 * 2;        // 16 MB
    bf16* mbf = (bf16*)w; w += (size_t)4 * 2048 * 2;           // 16 KB

    // R16: single fused preprocessing dispatch (was 4)
    pack_all<<<9992, 256, 0, stream>>>(x, xb, Wo, wob, mask, mbf,
                                       Wq, Wk, Wv, wt);

    // QKV projection: M=8192 N=3072 K=1024 (V masked in epilogue)
    gemm_nt<1><<<dim3(64, 24), 256, 0, stream>>>(
        xb, wt, qk, vT, bias, mask, 1024, 1024, 1024, 2048);

    // fused attention
    flash2<<<dim3(16, 32), 256, 0, stream>>>(qk, vT, mbf, mh);

    // out = mh @ Wo^T + b: M=8192 N=1024 K=1024, fp32 out
    gemm_nt<2><<<dim3(64, 8), 256, 0, stream>>>(
        mh, wob, out, nullptr, bias, nullptr, 1024, 1024, 1024, 1024);
}